// Round 4
// baseline (197.189 us; speedup 1.0000x reference)
//
#include <hip/hip_runtime.h>
#include <hip/hip_bf16.h>
#include <math.h>

typedef __bf16 bf16;
typedef bf16 bf16x2 __attribute__((ext_vector_type(2)));
typedef bf16 bf16x4 __attribute__((ext_vector_type(4)));
typedef bf16 bf16x8 __attribute__((ext_vector_type(8)));
typedef float f32x4 __attribute__((ext_vector_type(4)));
typedef float f32x16 __attribute__((ext_vector_type(16)));
typedef unsigned int u32x2 __attribute__((ext_vector_type(2)));
typedef unsigned int u32x4 __attribute__((ext_vector_type(4)));

#define B_   16
#define LQ_  256
#define LK_  4096
#define E_   64
#define H_   4
#define EK_  16
#define D_   32
#define LAT_ 32

// ws layout (bytes)
#define OFF_QP    0u          // bf16 [16][256][64]              = 512 KB
#define OFF_KP    524288u     // bf16 [16][4096][64]             = 8 MB
#define OFF_MVFB  8912896u    // bf16 [16][128 tile][2 ks][2 nd][64 lane][8] = 8 MB
#define OFF_WOT   17301504u   // bf16 [32][128]                  = 8 KB
#define OFF_NDP   17309696u   // f32  [8 kc][16 b][4 h][256 q][64] = 33.5 MB (num 0..31, den 32..63)
#define OFF_CNT   50864128u   // int  [128] last-block tickets (zeroed by prep each iter)
#define WS_NEED   50864640u

#define LOG2E 1.44269504f

__device__ inline f32x4 mfma_bf16(bf16x8 a, bf16x8 b, f32x4 c) {
  return __builtin_amdgcn_mfma_f32_16x16x32_bf16(a, b, c, 0, 0, 0);
}
__device__ inline f32x16 mfma_bf16_32(bf16x8 a, bf16x8 b, f32x16 c) {
  return __builtin_amdgcn_mfma_f32_32x32x16_bf16(a, b, c, 0, 0, 0);
}

// in-register lane32-half swap: a' = {a.lo, b.lo->hi}, b' = {a.hi->lo, b.hi}
__device__ inline void pl32swap(unsigned &a, unsigned &b) {
#if __has_builtin(__builtin_amdgcn_permlane32_swap)
  u32x2 r = __builtin_amdgcn_permlane32_swap(a, b, false, false);
  a = r[0]; b = r[1];
#else
  asm volatile("v_permlane32_swap_b32 %0, %1" : "+v"(a), "+v"(b));
#endif
}

// ---------------------------------------------------------------------------
// Kernel 0: prep.  blocks [0,32): q-proj, [32,544): k-proj, [544,800): mvfB,
// [800]: WoT + ticket zeroing.  Proj = MFMA GEMM rows x (64x64) W, +bias;
// q scaled by 0.25*log2e (folds 1/sqrt(ek) and the exp->exp2 conversion).
// mvfB is emitted as 32x32x16 B-frags: [b][tile][ks2][nd2][lane64][j8],
// lane = (col&31) + 32*((kk>>3)&1), ks = (kk>>4)&1, j = kk&7, nd = col>>5.
// ---------------------------------------------------------------------------
__global__ __launch_bounds__(256) void prep_kernel(
    const float* __restrict__ query, const float* __restrict__ key,
    const float* __restrict__ value, const int* __restrict__ mask,
    const float* __restrict__ Wq, const float* __restrict__ bq,
    const float* __restrict__ Wk, const float* __restrict__ bk,
    const float* __restrict__ Wo,
    bf16* __restrict__ qp, bf16* __restrict__ kp,
    bf16* __restrict__ mvfB, bf16* __restrict__ WoT, int* __restrict__ cnt)
{
  __shared__ __align__(16) bf16 s_b[16896];  // 33792 B, unioned across roles
  const int bid = blockIdx.x;
  const int tid = threadIdx.x;

  if (bid < 544) {
    // ---- projection role: 128 rows per block ----
    const bool isQ = bid < 32;
    const int row0 = isQ ? bid * 128 : (bid - 32) * 128;
    const float* in   = isQ ? query : key;
    const float* W    = isQ ? Wq : Wk;
    const float* bias = isQ ? bq : bk;
    bf16* outp        = isQ ? qp : kp;
    const float scal  = isQ ? (0.25f * LOG2E) : 1.0f;

    bf16* sIn = s_b;          // [128][72]
    bf16* sWT = s_b + 9216;   // [64][72]  (W^T: [col][k])

#pragma unroll
    for (int p = 0; p < 8; ++p) {
      int f4 = tid + p * 256;            // 2048 float4
      int row = f4 >> 4, e4 = (f4 & 15) * 4;
      float4 v = *(const float4*)(in + (size_t)(row0 + row) * 64 + e4);
      bf16x4 b4;
      b4[0] = (bf16)v.x; b4[1] = (bf16)v.y; b4[2] = (bf16)v.z; b4[3] = (bf16)v.w;
      *(bf16x4*)(sIn + row * 72 + e4) = b4;
    }
#pragma unroll
    for (int p = 0; p < 4; ++p) {
      int f4 = tid + p * 256;            // 1024 float4
      int k = f4 >> 4, c4 = (f4 & 15) * 4;
      float4 v = *(const float4*)(W + k * 64 + c4);
      sWT[(c4 + 0) * 72 + k] = (bf16)v.x;
      sWT[(c4 + 1) * 72 + k] = (bf16)v.y;
      sWT[(c4 + 2) * 72 + k] = (bf16)v.z;
      sWT[(c4 + 3) * 72 + k] = (bf16)v.w;
    }
    __syncthreads();

    const int w = tid >> 6, l = tid & 63, l15 = l & 15, g = l >> 4;
    f32x4 acc[2][4];
#pragma unroll
    for (int mt = 0; mt < 2; ++mt)
#pragma unroll
      for (int nt = 0; nt < 4; ++nt) acc[mt][nt] = f32x4{0.f, 0.f, 0.f, 0.f};

#pragma unroll
    for (int ks = 0; ks < 2; ++ks) {
      bf16x8 A0 = *(bf16x8*)(sIn + (32 * w + l15) * 72 + 32 * ks + 8 * g);
      bf16x8 A1 = *(bf16x8*)(sIn + (32 * w + 16 + l15) * 72 + 32 * ks + 8 * g);
#pragma unroll
      for (int nt = 0; nt < 4; ++nt) {
        bf16x8 Bf = *(bf16x8*)(sWT + (16 * nt + l15) * 72 + 32 * ks + 8 * g);
        acc[0][nt] = mfma_bf16(A0, Bf, acc[0][nt]);
        acc[1][nt] = mfma_bf16(A1, Bf, acc[1][nt]);
      }
    }
#pragma unroll
    for (int mt = 0; mt < 2; ++mt)
#pragma unroll
      for (int nt = 0; nt < 4; ++nt) {
        int col = 16 * nt + l15;
        float bv = bias[col];
#pragma unroll
        for (int r = 0; r < 4; ++r) {
          int row = row0 + 32 * w + 16 * mt + 4 * g + r;
          outp[(size_t)row * 64 + col] = (bf16)((acc[mt][nt][r] + bv) * scal);
        }
      }
  } else if (bid < 800) {
    // ---- mvfB role: 256-kk chunk -> bf16, 32x32x16-B-frag-ready layout ----
    const int rb = bid - 544;
    const int b = rb >> 4, kk0 = (rb & 15) * 256;
    // s_b as [col 64][kk 256 pad 264]
#pragma unroll
    for (int p = 0; p < 8; ++p) {
      int f4 = tid + p * 256;            // 2048 vec4 over [256 kk][32 d]
      int kk = f4 >> 3, d4 = (f4 & 7) * 4;
      size_t gi = ((size_t)(b * LK_ + kk0 + kk)) * 32 + d4;
      float4 v = *(const float4*)(value + gi);
      int4   m = *(const int4*)(mask + gi);
      s_b[(d4 + 0) * 264 + kk] = (bf16)(m.x ? v.x : 0.0f);
      s_b[(d4 + 1) * 264 + kk] = (bf16)(m.y ? v.y : 0.0f);
      s_b[(d4 + 2) * 264 + kk] = (bf16)(m.z ? v.z : 0.0f);
      s_b[(d4 + 3) * 264 + kk] = (bf16)(m.w ? v.w : 0.0f);
      s_b[(32 + d4 + 0) * 264 + kk] = (bf16)(float)m.x;
      s_b[(32 + d4 + 1) * 264 + kk] = (bf16)(float)m.y;
      s_b[(32 + d4 + 2) * 264 + kk] = (bf16)(float)m.z;
      s_b[(32 + d4 + 3) * 264 + kk] = (bf16)(float)m.w;
    }
    __syncthreads();
    // writeback: thread owns col = tid>>2, kk range [seg*64, seg*64+64)
    const int col = tid >> 2, seg = tid & 3;
    const int nd = col >> 5, n31 = col & 31;
#pragma unroll
    for (int w2 = 0; w2 < 8; ++w2) {
      int kkg = seg * 64 + w2 * 8;                 // 8-aligned, < 256
      int tile = (kk0 + kkg) >> 5;
      int ks   = (kkg >> 4) & 1;
      int hi2  = (kkg >> 3) & 1;
      int lane = n31 + 32 * hi2;
      uint4 d = *(uint4*)(s_b + col * 264 + kkg);
      *(uint4*)(mvfB + (size_t)((((b * 128 + tile) * 2 + ks) * 2 + nd) * 64 + lane) * 8) = d;
    }
  } else {
    // ---- WoT role: Wo[128][32] -> WoT[32][128] bf16; zero the 128 tickets ----
#pragma unroll
    for (int p = 0; p < 16; ++p) {
      int f = tid + p * 256;
      int k = f >> 5, n = f & 31;
      WoT[n * 128 + k] = (bf16)Wo[f];
    }
    if (tid < 128) cnt[tid] = 0;
  }
}

// ---------------------------------------------------------------------------
// Kernel 1: attention + fused output.  Main loop LDS-free (as r0): one
// 32x32x16 QK^T MFMA -> exp2 -> in-register permlane32 repack -> 4x 32x32x16
// PV MFMAs.  Each block writes its kc-partial to ndp, then the LAST of the 8
// kc-blocks per (b,qt) (release fence + atomicAdd ticket) reduces the 8
// partials (L2/L3-hot), divides, and applies x @ Wo + bo directly to out —
// eliminating the separate out_kernel dispatch and its cold ndp re-read.
// ---------------------------------------------------------------------------
__global__ __launch_bounds__(256, 4) void attn_kernel(
    const bf16* __restrict__ qp, const bf16* __restrict__ kp,
    const bf16* __restrict__ mvfB, float* __restrict__ ndp,
    const bf16* __restrict__ WoT, const float* __restrict__ bo,
    float* __restrict__ out, int* __restrict__ cnt)
{
  __shared__ __align__(16) bf16 s_x[32 * 136];  // [q 32][j 128 pad 136] (reducer)
  __shared__ int sLast;

  const int bid = blockIdx.x;
  const int kc = bid & 7, qt = (bid >> 3) & 7, b = bid >> 6;
  const int tid = threadIdx.x;
  const int h = tid >> 6, l = tid & 63;
  const int l31 = l & 31, hi = l >> 5;
  const int q0 = qt * 32;
  const int tile0 = kc * 16;   // tiles of 32 kk; 16 per block

  // persistent Q B-frag for 32x32x16: B[k=e][n=q], lane: n=l31, k=8*hi+j
  bf16x8 qB = *(const bf16x8*)(qp + (size_t)((b * LQ_ + q0 + l31) * 64 + h * EK_ + hi * 8));

  f32x16 accN, accD, Z;
#pragma unroll
  for (int i = 0; i < 16; ++i) { accN[i] = 0.f; accD[i] = 0.f; Z[i] = 0.f; }

  const bf16* mvt0 = mvfB + (size_t)(b * 128 + tile0) * 2048;  // 2*2*64*8 per tile
  const bf16* kp_b = kp + (size_t)(b * LK_ + tile0 * 32) * 64 + h * EK_ + hi * 8;

#pragma unroll 2
  for (int t = 0; t < 16; ++t) {
    const bf16* mvt = mvt0 + (size_t)t * 2048;

    // B-frags: (ks,nd) = (0,num),(0,den),(1,num),(1,den); coalesced 16B/lane
    bf16x8 Bn0 = *(const bf16x8*)(mvt + (0 * 64 + l) * 8);
    bf16x8 Bd0 = *(const bf16x8*)(mvt + (1 * 64 + l) * 8);
    bf16x8 Bn1 = *(const bf16x8*)(mvt + (2 * 64 + l) * 8);
    bf16x8 Bd1 = *(const bf16x8*)(mvt + (3 * 64 + l) * 8);

    // kA for 32x32x16: A[m=kk][k=e], lane: m=l31, k=8*hi+j — full wave
    bf16x8 kA = *(const bf16x8*)(kp_b + (size_t)(t * 32 + l31) * 64);

    // transposed scores: one 32x32x16 MFMA, S^T[kk 32][q 32], K=16 exact
    f32x16 S = mfma_bf16_32(kA, qB, Z);

    // exp2 (log2e folded into qp) -> 8 packed bf16 dwords
    unsigned P[8];
#pragma unroll
    for (int i = 0; i < 8; ++i) {
      union { bf16x2 hh; unsigned u; } cv;
      cv.hh[0] = (bf16)exp2f(S[2 * i + 0]);
      cv.hh[1] = (bf16)exp2f(S[2 * i + 1]);
      P[i] = cv.u;
    }
    // in-register transpose to 32x32x16 A-frag layout (lane m=l31, k=8*hi+j)
    pl32swap(P[0], P[2]);
    pl32swap(P[1], P[3]);
    pl32swap(P[4], P[6]);
    pl32swap(P[5], P[7]);
    union { u32x4 u; bf16x8 v; } pa0, pa1;
    pa0.u = (u32x4){P[0], P[1], P[2], P[3]};
    pa1.u = (u32x4){P[4], P[5], P[6], P[7]};

    // PV: 4x 32x32x16, acc[q32][col32] for num and den
    accN = mfma_bf16_32(pa0.v, Bn0, accN);
    accD = mfma_bf16_32(pa0.v, Bd0, accD);
    accN = mfma_bf16_32(pa1.v, Bn1, accN);
    accD = mfma_bf16_32(pa1.v, Bd1, accD);
  }

  // partial store: 32x32 D-layout: col=l31, row q=(r&3)+8*(r>>2)+4*hi
  float* ndp_w = ndp + ((((size_t)kc * B_ + b) * H_ + h) * LQ_ + q0) * 64;
#pragma unroll
  for (int r = 0; r < 16; ++r) {
    int q = (r & 3) + 8 * (r >> 2) + 4 * hi;
    ndp_w[(size_t)q * 64 + l31]      = accN[r];
    ndp_w[(size_t)q * 64 + 32 + l31] = accD[r];
  }

  // ---- last-block election (release: barrier drains stores, fence wb's L2) ----
  __syncthreads();
  if (tid == 0) {
    __threadfence();
    sLast = (atomicAdd(&cnt[b * 8 + qt], 1) == 7);
  }
  __syncthreads();
  if (!sLast) return;
  __threadfence();   // acquire: invalidate L1/L2 before reading other XCDs' partials
  __syncthreads();

  // ---- reduce 8 kc partials, x = num/den -> bf16 in LDS ----
  {
    const int q = tid >> 3, s = tid & 7;
    const int hh = s >> 1, dh = (s & 1) * 16;
    f32x4 n0 = f32x4{0.f,0.f,0.f,0.f}, n1 = n0, n2 = n0, n3 = n0;
    f32x4 e0 = n0, e1 = n0, e2 = n0, e3 = n0;
#pragma unroll
    for (int k = 0; k < 8; ++k) {
      const float* p = ndp + ((((size_t)k * B_ + b) * H_ + hh) * LQ_ + q0 + q) * 64 + dh;
      n0 += *(const f32x4*)(p + 0);
      n1 += *(const f32x4*)(p + 4);
      n2 += *(const f32x4*)(p + 8);
      n3 += *(const f32x4*)(p + 12);
      e0 += *(const f32x4*)(p + 32 + 0);
      e1 += *(const f32x4*)(p + 32 + 4);
      e2 += *(const f32x4*)(p + 32 + 8);
      e3 += *(const f32x4*)(p + 32 + 12);
    }
    bf16* sx = s_x + q * 136 + hh * 32 + dh;
#pragma unroll
    for (int i = 0; i < 4; ++i) {
      sx[i]      = (bf16)(n0[i] / e0[i]);
      sx[4 + i]  = (bf16)(n1[i] / e1[i]);
      sx[8 + i]  = (bf16)(n2[i] / e2[i]);
      sx[12 + i] = (bf16)(n3[i] / e3[i]);
    }
  }
  __syncthreads();

  // ---- out = x @ Wo + bo: 4 waves, wave (mq = w>>1, nt = w&1) does 16x16 ----
  {
    const int w = tid >> 6, l15 = l & 15, g = (l >> 4) & 3;
    const int mq = w >> 1, nt = w & 1;
    f32x4 acc2 = f32x4{0.f, 0.f, 0.f, 0.f};
#pragma unroll
    for (int ks = 0; ks < 4; ++ks) {
      bf16x8 A  = *(bf16x8*)(s_x + (16 * mq + l15) * 136 + 32 * ks + 8 * g);
      bf16x8 Bf = *(const bf16x8*)(WoT + (16 * nt + l15) * 128 + 32 * ks + 8 * g);
      acc2 = mfma_bf16(A, Bf, acc2);
    }
    float bv = bo[16 * nt + l15];
#pragma unroll
    for (int r = 0; r < 4; ++r) {
      int row = q0 + 16 * mq + 4 * g + r;
      out[(size_t)(b * LQ_ + row) * LAT_ + 16 * nt + l15] = acc2[r] + bv;
    }
  }
}

extern "C" void kernel_launch(void* const* d_in, const int* in_sizes, int n_in,
                              void* d_out, int out_size, void* d_ws, size_t ws_size,
                              hipStream_t stream) {
  const float* query = (const float*)d_in[0];
  const float* key   = (const float*)d_in[1];
  const float* value = (const float*)d_in[2];
  const int*   mask  = (const int*)d_in[3];
  const float* Wq    = (const float*)d_in[4];
  const float* bq    = (const float*)d_in[5];
  const float* Wk    = (const float*)d_in[6];
  const float* bk    = (const float*)d_in[7];
  const float* Wo    = (const float*)d_in[8];
  const float* bo    = (const float*)d_in[9];
  float* out = (float*)d_out;
  char* ws = (char*)d_ws;

  if (ws_size < (size_t)WS_NEED) return;  // diagnostic: leaves out == 0

  bf16* qp   = (bf16*)(ws + OFF_QP);
  bf16* kp   = (bf16*)(ws + OFF_KP);
  bf16* mvfB = (bf16*)(ws + OFF_MVFB);
  bf16* WoT  = (bf16*)(ws + OFF_WOT);
  float* ndp = (float*)(ws + OFF_NDP);
  int*   cnt = (int*)(ws + OFF_CNT);

  prep_kernel<<<801, 256, 0, stream>>>(query, key, value, mask, Wq, bq, Wk, bk,
                                       Wo, qp, kp, mvfB, WoT, cnt);
  attn_kernel<<<1024, 256, 0, stream>>>(qp, kp, mvfB, ndp, WoT, bo, out, cnt);
}

// Round 5
// 125.516 us; speedup vs baseline: 1.5710x; 1.5710x over previous
//
#include <hip/hip_runtime.h>
#include <hip/hip_bf16.h>
#include <math.h>

typedef __bf16 bf16;
typedef bf16 bf16x2 __attribute__((ext_vector_type(2)));
typedef bf16 bf16x4 __attribute__((ext_vector_type(4)));
typedef bf16 bf16x8 __attribute__((ext_vector_type(8)));
typedef float f32x4 __attribute__((ext_vector_type(4)));
typedef float f32x16 __attribute__((ext_vector_type(16)));
typedef unsigned int u32x2 __attribute__((ext_vector_type(2)));
typedef unsigned int u32x4 __attribute__((ext_vector_type(4)));

#define B_   16
#define LQ_  256
#define LK_  4096
#define E_   64
#define H_   4
#define EK_  16
#define D_   32
#define LAT_ 32

// ws layout (bytes)
#define OFF_QP    0u          // bf16 [16][256][64]              = 512 KB
#define OFF_KP    524288u     // bf16 [16][4096][64]             = 8 MB
#define OFF_MVFB  8912896u    // bf16 [16][128 tile][2 ks][2 nd][64 lane][8] = 8 MB
#define OFF_WOT   17301504u   // bf16 [32][128]                  = 8 KB
#define OFF_NDP   17309696u   // f32  [8 kc][16 b][4 h][256 q][64] = 33.5 MB (num 0..31, den 32..63)
#define WS_NEED   50864128u

#define LOG2E 1.44269504f

__device__ inline f32x4 mfma_bf16(bf16x8 a, bf16x8 b, f32x4 c) {
  return __builtin_amdgcn_mfma_f32_16x16x32_bf16(a, b, c, 0, 0, 0);
}
__device__ inline f32x16 mfma_bf16_32(bf16x8 a, bf16x8 b, f32x16 c) {
  return __builtin_amdgcn_mfma_f32_32x32x16_bf16(a, b, c, 0, 0, 0);
}

// in-register lane32-half swap: a' = {a.lo, b.lo->hi}, b' = {a.hi->lo, b.hi}
__device__ inline void pl32swap(unsigned &a, unsigned &b) {
#if __has_builtin(__builtin_amdgcn_permlane32_swap)
  u32x2 r = __builtin_amdgcn_permlane32_swap(a, b, false, false);
  a = r[0]; b = r[1];
#else
  asm volatile("v_permlane32_swap_b32 %0, %1" : "+v"(a), "+v"(b));
#endif
}

// ---------------------------------------------------------------------------
// Kernel 0: prep.  blocks [0,32): q-proj, [32,544): k-proj, [544,800): mvfB,
// [800]: WoT.  Proj = MFMA GEMM computing (XW)^T via swapped operands
// (A = W^T rows, B = X rows): lane reg-quad = 4 consecutive e of one row
// -> bf16x4 (8B) stores instead of 32 scalar 2B stores.  q scaled by
// 0.25*log2e (folds 1/sqrt(ek) and the exp->exp2 conversion).
// mvfB emitted as 32x32x16 B-frags: [b][tile][ks2][nd2][lane64][j8],
// lane = (col&31) + 32*((kk>>3)&1), ks = (kk>>4)&1, j = kk&7, nd = col>>5.
// mvfB staging: per-thread 4kk x 4d block, in-register repack, ds_write_b64
// (8x fewer LDS write instructions than scalar transpose).
// ---------------------------------------------------------------------------
__global__ __launch_bounds__(256) void prep_kernel(
    const float* __restrict__ query, const float* __restrict__ key,
    const float* __restrict__ value, const int* __restrict__ mask,
    const float* __restrict__ Wq, const float* __restrict__ bq,
    const float* __restrict__ Wk, const float* __restrict__ bk,
    const float* __restrict__ Wo,
    bf16* __restrict__ qp, bf16* __restrict__ kp,
    bf16* __restrict__ mvfB, bf16* __restrict__ WoT)
{
  __shared__ __align__(16) bf16 s_b[16896];  // 33792 B, unioned across roles
  const int bid = blockIdx.x;
  const int tid = threadIdx.x;

  if (bid < 544) {
    // ---- projection role: 128 rows per block ----
    const bool isQ = bid < 32;
    const int row0 = isQ ? bid * 128 : (bid - 32) * 128;
    const float* in   = isQ ? query : key;
    const float* W    = isQ ? Wq : Wk;
    const float* bias = isQ ? bq : bk;
    bf16* outp        = isQ ? qp : kp;
    const float scal  = isQ ? (0.25f * LOG2E) : 1.0f;

    bf16* sIn = s_b;          // [128][72]
    bf16* sWT = s_b + 9216;   // [64][72]  (W^T: [col][k])

#pragma unroll
    for (int p = 0; p < 8; ++p) {
      int f4 = tid + p * 256;            // 2048 float4
      int row = f4 >> 4, e4 = (f4 & 15) * 4;
      float4 v = *(const float4*)(in + (size_t)(row0 + row) * 64 + e4);
      bf16x4 b4;
      b4[0] = (bf16)v.x; b4[1] = (bf16)v.y; b4[2] = (bf16)v.z; b4[3] = (bf16)v.w;
      *(bf16x4*)(sIn + row * 72 + e4) = b4;
    }
#pragma unroll
    for (int p = 0; p < 4; ++p) {
      int f4 = tid + p * 256;            // 1024 float4
      int k = f4 >> 4, c4 = (f4 & 15) * 4;
      float4 v = *(const float4*)(W + k * 64 + c4);
      sWT[(c4 + 0) * 72 + k] = (bf16)v.x;
      sWT[(c4 + 1) * 72 + k] = (bf16)v.y;
      sWT[(c4 + 2) * 72 + k] = (bf16)v.z;
      sWT[(c4 + 3) * 72 + k] = (bf16)v.w;
    }
    __syncthreads();

    const int w = tid >> 6, l = tid & 63, l15 = l & 15, g = l >> 4;
    // D^T tiles: acc[et][rt] -> e = 16*et + 4*g + r, row = 32*w + 16*rt + l15
    f32x4 acc[4][2];
#pragma unroll
    for (int et = 0; et < 4; ++et)
#pragma unroll
      for (int rt = 0; rt < 2; ++rt) acc[et][rt] = f32x4{0.f, 0.f, 0.f, 0.f};

#pragma unroll
    for (int ks = 0; ks < 2; ++ks) {
      bf16x8 X0 = *(bf16x8*)(sIn + (32 * w + l15) * 72 + 32 * ks + 8 * g);
      bf16x8 X1 = *(bf16x8*)(sIn + (32 * w + 16 + l15) * 72 + 32 * ks + 8 * g);
#pragma unroll
      for (int et = 0; et < 4; ++et) {
        bf16x8 Wf = *(bf16x8*)(sWT + (16 * et + l15) * 72 + 32 * ks + 8 * g);
        acc[et][0] = mfma_bf16(Wf, X0, acc[et][0]);
        acc[et][1] = mfma_bf16(Wf, X1, acc[et][1]);
      }
    }
#pragma unroll
    for (int et = 0; et < 4; ++et) {
      f32x4 bv = *(const f32x4*)(bias + 16 * et + 4 * g);  // e-quad bias
#pragma unroll
      for (int rt = 0; rt < 2; ++rt) {
        int row = row0 + 32 * w + 16 * rt + l15;
        bf16x4 o;
#pragma unroll
        for (int r = 0; r < 4; ++r) o[r] = (bf16)((acc[et][rt][r] + bv[r]) * scal);
        *(bf16x4*)(outp + (size_t)row * 64 + 16 * et + 4 * g) = o;
      }
    }
  } else if (bid < 800) {
    // ---- mvfB role: 256-kk chunk -> bf16, 32x32x16-B-frag-ready layout ----
    const int rb = bid - 544;
    const int b = rb >> 4, kk0 = (rb & 15) * 256;
    // s_b as [col 64][kk 256 pad 264]; thread unit = 4 kk x 4 d block
#pragma unroll
    for (int p = 0; p < 2; ++p) {
      int unit = tid + p * 256;          // 512 units: 8 d-groups x 64 kk-groups
      int d4 = (unit & 7) * 4;           // 0..28
      int kk = (unit >> 3) * 4;          // 0..252
      size_t gi = ((size_t)(b * LK_ + kk0 + kk)) * 32 + d4;
      float4 v0 = *(const float4*)(value + gi);
      float4 v1 = *(const float4*)(value + gi + 32);
      float4 v2 = *(const float4*)(value + gi + 64);
      float4 v3 = *(const float4*)(value + gi + 96);
      int4 m0 = *(const int4*)(mask + gi);
      int4 m1 = *(const int4*)(mask + gi + 32);
      int4 m2 = *(const int4*)(mask + gi + 64);
      int4 m3 = *(const int4*)(mask + gi + 96);
      const float* fv[4] = {(const float*)&v0, (const float*)&v1,
                            (const float*)&v2, (const float*)&v3};
      const int*   fm[4] = {(const int*)&m0, (const int*)&m1,
                            (const int*)&m2, (const int*)&m3};
#pragma unroll
      for (int dd = 0; dd < 4; ++dd) {
        bf16x4 a, mk;
#pragma unroll
        for (int i = 0; i < 4; ++i) {
          int mm = fm[i][dd];
          a[i]  = (bf16)(mm ? fv[i][dd] : 0.0f);
          mk[i] = (bf16)(float)mm;
        }
        *(bf16x4*)(s_b + (d4 + dd) * 264 + kk)      = a;   // masked value
        *(bf16x4*)(s_b + (32 + d4 + dd) * 264 + kk) = mk;  // mask
      }
    }
    __syncthreads();
    // writeback: thread owns col = tid>>2, kk range [seg*64, seg*64+64)
    const int col = tid >> 2, seg = tid & 3;
    const int nd = col >> 5, n31 = col & 31;
#pragma unroll
    for (int w2 = 0; w2 < 8; ++w2) {
      int kkg = seg * 64 + w2 * 8;                 // 8-aligned, < 256
      int tile = (kk0 + kkg) >> 5;
      int ks   = (kkg >> 4) & 1;
      int hi2  = (kkg >> 3) & 1;
      int lane = n31 + 32 * hi2;
      uint4 d = *(uint4*)(s_b + col * 264 + kkg);
      *(uint4*)(mvfB + (size_t)((((b * 128 + tile) * 2 + ks) * 2 + nd) * 64 + lane) * 8) = d;
    }
  } else {
    // ---- WoT role: Wo[128][32] -> WoT[32][128] bf16 ----
#pragma unroll
    for (int p = 0; p < 16; ++p) {
      int f = tid + p * 256;
      int k = f >> 5, n = f & 31;
      WoT[n * 128 + k] = (bf16)Wo[f];
    }
  }
}

// ---------------------------------------------------------------------------
// Kernel 1: attention — LDS-free.  Scores: one 32x32x16 MFMA producing
// S^T[kk32][q32] (col=lane&31=q, row kk=(reg&3)+8*(reg>>2)+4*(lane>>5)).
// P = exp2(S) is packed to bf16 dwords with cvt_pk, then 4 permlane32_swap
// per tile rearrange them IN REGISTERS into the 32x32x16 A-frag layout
// (lane m=l31, k=8*hi+j), eliminating the per-tile LDS write/read round trip.
// PV: 4x 32x32x16 MFMAs (2 K-halves x num/den) vs 32x32x16 B-frags of mvfB.
// ---------------------------------------------------------------------------
__global__ __launch_bounds__(256, 4) void attn_kernel(
    const bf16* __restrict__ qp, const bf16* __restrict__ kp,
    const bf16* __restrict__ mvfB, float* __restrict__ ndp)
{
  const int bid = blockIdx.x;
  const int kc = bid & 7, qt = (bid >> 3) & 7, b = bid >> 6;
  const int tid = threadIdx.x;
  const int h = tid >> 6, l = tid & 63;
  const int l31 = l & 31, hi = l >> 5;
  const int q0 = qt * 32;
  const int tile0 = kc * 16;   // tiles of 32 kk; 16 per block

  // persistent Q B-frag for 32x32x16: B[k=e][n=q], lane: n=l31, k=8*hi+j
  bf16x8 qB = *(const bf16x8*)(qp + (size_t)((b * LQ_ + q0 + l31) * 64 + h * EK_ + hi * 8));

  f32x16 accN, accD, Z;
#pragma unroll
  for (int i = 0; i < 16; ++i) { accN[i] = 0.f; accD[i] = 0.f; Z[i] = 0.f; }

  const bf16* mvt0 = mvfB + (size_t)(b * 128 + tile0) * 2048;  // 2*2*64*8 per tile
  const bf16* kp_b = kp + (size_t)(b * LK_ + tile0 * 32) * 64 + h * EK_ + hi * 8;

#pragma unroll 2
  for (int t = 0; t < 16; ++t) {
    const bf16* mvt = mvt0 + (size_t)t * 2048;

    // B-frags: (ks,nd) = (0,num),(0,den),(1,num),(1,den); coalesced 16B/lane
    bf16x8 Bn0 = *(const bf16x8*)(mvt + (0 * 64 + l) * 8);
    bf16x8 Bd0 = *(const bf16x8*)(mvt + (1 * 64 + l) * 8);
    bf16x8 Bn1 = *(const bf16x8*)(mvt + (2 * 64 + l) * 8);
    bf16x8 Bd1 = *(const bf16x8*)(mvt + (3 * 64 + l) * 8);

    // kA for 32x32x16: A[m=kk][k=e], lane: m=l31, k=8*hi+j — full wave
    bf16x8 kA = *(const bf16x8*)(kp_b + (size_t)(t * 32 + l31) * 64);

    // transposed scores: one 32x32x16 MFMA, S^T[kk 32][q 32], K=16 exact
    f32x16 S = mfma_bf16_32(kA, qB, Z);

    // exp2 (log2e folded into qp) -> 8 packed bf16 dwords
    unsigned P[8];
#pragma unroll
    for (int i = 0; i < 8; ++i) {
      union { bf16x2 hh; unsigned u; } cv;
      cv.hh[0] = (bf16)exp2f(S[2 * i + 0]);
      cv.hh[1] = (bf16)exp2f(S[2 * i + 1]);
      P[i] = cv.u;
    }
    // in-register transpose to 32x32x16 A-frag layout (lane m=l31, k=8*hi+j)
    pl32swap(P[0], P[2]);
    pl32swap(P[1], P[3]);
    pl32swap(P[4], P[6]);
    pl32swap(P[5], P[7]);
    union { u32x4 u; bf16x8 v; } pa0, pa1;
    pa0.u = (u32x4){P[0], P[1], P[2], P[3]};
    pa1.u = (u32x4){P[4], P[5], P[6], P[7]};

    // PV: 4x 32x32x16, acc[q32][col32] for num and den
    accN = mfma_bf16_32(pa0.v, Bn0, accN);
    accD = mfma_bf16_32(pa0.v, Bd0, accD);
    accN = mfma_bf16_32(pa1.v, Bn1, accN);
    accD = mfma_bf16_32(pa1.v, Bd1, accD);
  }

  // epilogue: 32x32 D-layout: col=l31, row q=(r&3)+8*(r>>2)+4*hi
  float* ndp_w = ndp + ((((size_t)kc * B_ + b) * H_ + h) * LQ_ + q0) * 64;
#pragma unroll
  for (int r = 0; r < 16; ++r) {
    int q = (r & 3) + 8 * (r >> 2) + 4 * hi;
    ndp_w[(size_t)q * 64 + l31]      = accN[r];
    ndp_w[(size_t)q * 64 + 32 + l31] = accD[r];
  }
}

// ---------------------------------------------------------------------------
// Kernel 2: reduce 8 kc-partials, x = num/den -> bf16 -> out = x @ Wo + bo.
// grid 256 (b, 16-q tile).
// ---------------------------------------------------------------------------
__global__ __launch_bounds__(256) void out_kernel(
    const float* __restrict__ ndp, const bf16* __restrict__ WoT,
    const float* __restrict__ bo, float* __restrict__ out)
{
  __shared__ __align__(16) bf16 s_x[16 * 136];  // [q 16][j 128 pad 136]
  const int bid = blockIdx.x;
  const int b = bid >> 4, q0 = (bid & 15) * 16;
  const int tid = threadIdx.x;
  const int q = tid >> 4, jg = tid & 15;
  const int h = jg >> 2, d0 = (jg & 3) * 8;

  f32x4 nlo = f32x4{0.f,0.f,0.f,0.f}, nhi = f32x4{0.f,0.f,0.f,0.f};
  f32x4 dlo = f32x4{0.f,0.f,0.f,0.f}, dhi = f32x4{0.f,0.f,0.f,0.f};
#pragma unroll
  for (int kc = 0; kc < 8; ++kc) {
    const float* p = ndp + ((((size_t)kc * B_ + b) * H_ + h) * LQ_ + q0 + q) * 64;
    nlo += *(const f32x4*)(p + d0);
    nhi += *(const f32x4*)(p + d0 + 4);
    dlo += *(const f32x4*)(p + 32 + d0);
    dhi += *(const f32x4*)(p + 32 + d0 + 4);
  }
  bf16* sx = s_x + q * 136 + h * 32 + d0;
#pragma unroll
  for (int i = 0; i < 4; ++i) {
    sx[i]     = (bf16)(nlo[i] / dlo[i]);
    sx[4 + i] = (bf16)(nhi[i] / dhi[i]);
  }
  __syncthreads();
  const int w = tid >> 6, l = tid & 63, l15 = l & 15, g = l >> 4;
  if (w < 2) {
    const int nt = w;
    f32x4 acc = f32x4{0.f, 0.f, 0.f, 0.f};
#pragma unroll
    for (int ks = 0; ks < 4; ++ks) {
      bf16x8 A  = *(bf16x8*)(s_x + l15 * 136 + 32 * ks + 8 * g);
      bf16x8 Bf = *(const bf16x8*)(WoT + (l15 + 16 * nt) * 128 + 32 * ks + 8 * g);
      acc = mfma_bf16(A, Bf, acc);
    }
    float bv = bo[l15 + 16 * nt];
#pragma unroll
    for (int r = 0; r < 4; ++r) {
      int row = q0 + 4 * g + r;
      out[(size_t)(b * LQ_ + row) * LAT_ + l15 + 16 * nt] = acc[r] + bv;
    }
  }
}

extern "C" void kernel_launch(void* const* d_in, const int* in_sizes, int n_in,
                              void* d_out, int out_size, void* d_ws, size_t ws_size,
                              hipStream_t stream) {
  const float* query = (const float*)d_in[0];
  const float* key   = (const float*)d_in[1];
  const float* value = (const float*)d_in[2];
  const int*   mask  = (const int*)d_in[3];
  const float* Wq    = (const float*)d_in[4];
  const float* bq    = (const float*)d_in[5];
  const float* Wk    = (const float*)d_in[6];
  const float* bk    = (const float*)d_in[7];
  const float* Wo    = (const float*)d_in[8];
  const float* bo    = (const float*)d_in[9];
  float* out = (float*)d_out;
  char* ws = (char*)d_ws;

  if (ws_size < (size_t)WS_NEED) return;  // diagnostic: leaves out == 0

  bf16* qp   = (bf16*)(ws + OFF_QP);
  bf16* kp   = (bf16*)(ws + OFF_KP);
  bf16* mvfB = (bf16*)(ws + OFF_MVFB);
  bf16* WoT  = (bf16*)(ws + OFF_WOT);
  float* ndp = (float*)(ws + OFF_NDP);

  prep_kernel<<<801, 256, 0, stream>>>(query, key, value, mask, Wq, bq, Wk, bk,
                                       Wo, qp, kp, mvfB, WoT);
  attn_kernel<<<1024, 256, 0, stream>>>(qp, kp, mvfB, ndp);
  out_kernel<<<256, 256, 0, stream>>>(ndp, WoT, bo, out);
}